// Round 18
// baseline (69.536 us; speedup 1.0000x reference)
//
#include <hip/hip_runtime.h>

#define BATCH 8
#define NBOX 4096
#define NCLS 80
#define THRESH 0.8f
#define EPSV 1e-9f
#define WAVES 4
#define TPB (WAVES * 64)     // 256 threads
#define PERW (NBOX / WAVES)  // 1024 indices per wave
#define WITER (PERW / 64)    // 16 ballot iterations per wave
#define WCAP 64              // per-wave segment cap (mean class hits/quarter ~13)

// One 4-wave block per (batch, class). Single-pass wave-local stable
// compaction (wave w -> lbox[w*WCAP..]); segments walked in wave order =
// ascending original index (reference FP term order). Exact j != i test.
__global__ __launch_bounds__(TPB) void class_filter_kernel(
    const float* __restrict__ boxes,   // [B,N,4]
    const int* __restrict__ cls,       // [B,N]
    float* __restrict__ out)           // [B*N*4] masked boxes, then [B*N] keep
{
    __shared__ float4 lbox[WAVES * WCAP];
    __shared__ float  larea[WAVES * WCAP];
    __shared__ int    lidx[WAVES * WCAP];
    __shared__ int    wcnt[WAVES];

    const int b = blockIdx.x / NCLS;
    const int c = blockIdx.x % NCLS;
    const int tid  = threadIdx.x;
    const int w    = tid >> 6;
    const int lane = tid & 63;
    const int w0   = w * PERW;

    const float4* bx = reinterpret_cast<const float4*>(boxes) + (size_t)b * NBOX;
    const int* cl = cls + (size_t)b * NBOX;

    // prefetch this wave's classes (16 independent loads, latency off the chain)
    int myc[WITER];
#pragma unroll
    for (int it = 0; it < WITER; ++it) myc[it] = cl[w0 + it * 64 + lane];

    // single-pass wave-local stable compaction
    int run = 0;
#pragma unroll
    for (int it = 0; it < WITER; ++it) {
        const bool m = (myc[it] == c);
        const unsigned long long mask = __ballot(m);
        const int pos = run + (int)__popcll(mask & ((1ull << lane) - 1ull));
        if (m && pos < WCAP) {
            const int idx = w0 + it * 64 + lane;
            float4 bb = bx[idx];
            lbox[w * WCAP + pos]  = bb;
            larea[w * WCAP + pos] = (bb.z - bb.x) * (bb.w - bb.y);
            lidx[w * WCAP + pos]  = idx;
        }
        run += (int)__popcll(mask);
    }
    if (lane == 0) wcnt[w] = run;
    __syncthreads();

    int psum[WAVES + 1];
    psum[0] = 0;
    bool ovf = false;
#pragma unroll
    for (int ww = 0; ww < WAVES; ++ww) {
        int v = wcnt[ww];
        ovf |= (v > WCAP);
        psum[ww + 1] = psum[ww] + v;
    }
    const int len = psum[WAVES];

    float*  keepOut = out + (size_t)BATCH * NBOX * 4;
    float4* boxOut  = reinterpret_cast<float4*>(out);

    if (!ovf) {
        for (int ib = 0; ib < len; ib += TPB) {
            const int ir = ib + tid;
            const bool act = ir < len;
            int wsel = 0;
#pragma unroll
            for (int ww = 1; ww < WAVES; ++ww) if (ir >= psum[ww]) wsel = ww;
            const int sl = act ? (wsel * WCAP + (ir - psum[wsel])) : 0;
            float4 bi = act ? lbox[sl] : make_float4(2.f, 2.f, -1.f, -1.f);
            const int mi = act ? lidx[sl] : -1;
            float sum = 0.f;
#pragma unroll 1
            for (int ww = 0; ww < WAVES; ++ww) {      // wave order = index order
                const int n = wcnt[ww];
                for (int k = 0; k < n; ++k) {         // broadcast LDS reads
                    float4 bj = lbox[ww * WCAP + k];
                    float m = fmaxf(fmaxf(bi.x - bj.x, bi.y - bj.y),
                                    fmaxf(bj.z - bi.z, bj.w - bi.w));
                    bool cont = (m <= 0.f) && (lidx[ww * WCAP + k] != mi);
                    sum += cont ? larea[ww * WCAP + k] : 0.f;
                }
            }
            if (act) {
                float area = larea[sl];
                float kf = (sum <= THRESH * (area + EPSV)) ? 1.f : 0.f;
                const int g = b * NBOX + mi;
                boxOut[g] = make_float4(bi.x * kf, bi.y * kf, bi.z * kf, bi.w * kf);
                keepOut[g] = kf;
            }
        }
    } else {
        // general fallback (not expected with this input): direct global scan
        for (int i0 = 0; i0 < NBOX; i0 += TPB) {
            const int i = i0 + tid;
            if (cl[i] != c) continue;
            float4 bi = bx[i];
            float area = (bi.z - bi.x) * (bi.w - bi.y);
            float sum = 0.f;
            for (int j = 0; j < NBOX; ++j) {
                if (cl[j] != c || j == i) continue;
                float4 bj = bx[j];
                float m = fmaxf(fmaxf(bi.x - bj.x, bi.y - bj.y),
                                fmaxf(bj.z - bi.z, bj.w - bi.w));
                sum += (m <= 0.f) ? (bj.z - bj.x) * (bj.w - bj.y) : 0.f;
            }
            float kf = (sum <= THRESH * (area + EPSV)) ? 1.f : 0.f;
            const int g = b * NBOX + i;
            boxOut[g] = make_float4(bi.x * kf, bi.y * kf, bi.z * kf, bi.w * kf);
            keepOut[g] = kf;
        }
    }
}

extern "C" void kernel_launch(void* const* d_in, const int* in_sizes, int n_in,
                              void* d_out, int out_size, void* d_ws, size_t ws_size,
                              hipStream_t stream) {
    const float* boxes = (const float*)d_in[0];
    const int*   cls   = (const int*)d_in[1];
    float* out = (float*)d_out;

    class_filter_kernel<<<BATCH * NCLS, TPB, 0, stream>>>(boxes, cls, out);
}

// Round 19
// 59.879 us; speedup vs baseline: 1.1613x; 1.1613x over previous
//
#include <hip/hip_runtime.h>

#define BATCH 8
#define NBOX 4096
#define NCLS 80
#define THRESH 0.8f
#define EPSV 1e-9f
#define WAVES 4
#define TPB (WAVES * 64)     // 256 threads
#define PERW (NBOX / WAVES)  // 1024 indices per wave
#define WITER (PERW / 64)    // 16 ballot iterations per wave
#define WCAP 96              // per-wave cap (mean 12.8/quarter, 23 sd margin)
#define LCAP (WAVES * WCAP)  // 384 flat capacity

// One 4-wave block per (batch, class), three phases:
//  1) ballot-compact ORIGINAL INDICES into wave-local LDS segments (register-
//     only chain: classes prefetched, no global loads inside the chain)
//  2) flat gather: thread t < len loads box[segIdx[t]] -- all scattered loads
//     issued in parallel -- into flat LDS arrays (ascending original index)
//  3) all-pairs over the flat segment, exact j != i by index; direct output.
__global__ __launch_bounds__(TPB) void class_filter_kernel(
    const float* __restrict__ boxes,   // [B,N,4]
    const int* __restrict__ cls,       // [B,N]
    float* __restrict__ out)           // [B*N*4] masked boxes, then [B*N] keep
{
    __shared__ int    segIdx[LCAP];    // wave-segmented original indices
    __shared__ int    wcnt[WAVES];
    __shared__ float4 lbox[LCAP];      // flat, ascending original index
    __shared__ float2 lai[LCAP];       // (area, idx-bits) packed -> 1 b64 read

    const int b = blockIdx.x / NCLS;
    const int c = blockIdx.x % NCLS;
    const int tid  = threadIdx.x;
    const int w    = tid >> 6;
    const int lane = tid & 63;
    const int w0   = w * PERW;

    const float4* bx = reinterpret_cast<const float4*>(boxes) + (size_t)b * NBOX;
    const int* cl = cls + (size_t)b * NBOX;

    // prefetch this wave's classes (16 coalesced dword loads, all independent)
    int myc[WITER];
#pragma unroll
    for (int it = 0; it < WITER; ++it) myc[it] = cl[w0 + it * 64 + lane];

    // phase 1: register-only ballot compaction of indices
    int run = 0;
#pragma unroll
    for (int it = 0; it < WITER; ++it) {
        const bool m = (myc[it] == c);
        const unsigned long long mask = __ballot(m);
        const int pos = run + (int)__popcll(mask & ((1ull << lane) - 1ull));
        if (m && pos < WCAP) segIdx[w * WCAP + pos] = w0 + it * 64 + lane;
        run += (int)__popcll(mask);
    }
    if (lane == 0) wcnt[w] = run;
    __syncthreads();

    int psum[WAVES + 1];
    psum[0] = 0;
    bool ovf = false;
#pragma unroll
    for (int ww = 0; ww < WAVES; ++ww) {
        int v = wcnt[ww];
        ovf |= (v > WCAP);
        psum[ww + 1] = psum[ww] + v;
    }
    const int len = psum[WAVES];   // <= LCAP = 384 when !ovf

    float*  keepOut = out + (size_t)BATCH * NBOX * 4;
    float4* boxOut  = reinterpret_cast<float4*>(out);

    if (!ovf) {
        // phase 2: parallel flat gather (one scattered load per matched box)
        if (tid < len) {
            int wsel = 0;
#pragma unroll
            for (int ww = 1; ww < WAVES; ++ww) if (tid >= psum[ww]) wsel = ww;
            const int idx = segIdx[wsel * WCAP + (tid - psum[wsel])];
            float4 bb = bx[idx];
            lbox[tid] = bb;
            lai[tid]  = make_float2((bb.z - bb.x) * (bb.w - bb.y),
                                    __int_as_float(idx));
        }
        __syncthreads();

        // phase 3: all-pairs, k ascending original index (reference FP order)
        if (tid < len) {
            const float4 bi = lbox[tid];
            const int mi = __float_as_int(lai[tid].y);
            float sum = 0.f;
            for (int k = 0; k < len; ++k) {          // broadcast LDS reads
                float4 bj = lbox[k];
                float2 aj = lai[k];
                float m = fmaxf(fmaxf(bi.x - bj.x, bi.y - bj.y),
                                fmaxf(bj.z - bi.z, bj.w - bi.w));
                bool cont = (m <= 0.f) && (__float_as_int(aj.y) != mi);
                sum += cont ? aj.x : 0.f;
            }
            const float area = lai[tid].x;
            const float kf = (sum <= THRESH * (area + EPSV)) ? 1.f : 0.f;
            const int g = b * NBOX + mi;
            boxOut[g] = make_float4(bi.x * kf, bi.y * kf, bi.z * kf, bi.w * kf);
            keepOut[g] = kf;
        }
    } else {
        // general fallback (not expected with this input): direct global scan
        for (int i0 = 0; i0 < NBOX; i0 += TPB) {
            const int i = i0 + tid;
            if (cl[i] != c) continue;
            float4 bi = bx[i];
            float area = (bi.z - bi.x) * (bi.w - bi.y);
            float sum = 0.f;
            for (int j = 0; j < NBOX; ++j) {
                if (cl[j] != c || j == i) continue;
                float4 bj = bx[j];
                float m = fmaxf(fmaxf(bi.x - bj.x, bi.y - bj.y),
                                fmaxf(bj.z - bi.z, bj.w - bi.w));
                sum += (m <= 0.f) ? (bj.z - bj.x) * (bj.w - bj.y) : 0.f;
            }
            float kf = (sum <= THRESH * (area + EPSV)) ? 1.f : 0.f;
            const int g = b * NBOX + i;
            boxOut[g] = make_float4(bi.x * kf, bi.y * kf, bi.z * kf, bi.w * kf);
            keepOut[g] = kf;
        }
    }
}

extern "C" void kernel_launch(void* const* d_in, const int* in_sizes, int n_in,
                              void* d_out, int out_size, void* d_ws, size_t ws_size,
                              hipStream_t stream) {
    const float* boxes = (const float*)d_in[0];
    const int*   cls   = (const int*)d_in[1];
    float* out = (float*)d_out;

    class_filter_kernel<<<BATCH * NCLS, TPB, 0, stream>>>(boxes, cls, out);
}